// Round 2
// baseline (473.464 us; speedup 1.0000x reference)
//
#include <hip/hip_runtime.h>
#include <hip/hip_bf16.h>
#include <hip/hip_cooperative_groups.h>

namespace cg = cooperative_groups;

#define N 2048
#define NM1 2047
#define DT 256
#define ET 32
#define EC 128
#define NC 5
#define FS 80    // feats row stride (floats)
#define FD 69    // used feature cols
#define KC_ET 16 // k-chunks for ET GEMMs (chunk = 128)
#define KC_EC 16 // k-chunks for EC GEMM (chunk = 128)
#define SMEM_MAX 55296

typedef unsigned short u16;
typedef float f32x4 __attribute__((ext_vector_type(4)));
typedef __bf16 bf16x8 __attribute__((ext_vector_type(8)));

__device__ inline u16 bf16_rne(float x){
    unsigned int b = __float_as_uint(x);
    b += 0x7fffu + ((b >> 16) & 1u);
    return (u16)(b >> 16);
}
__device__ inline float bf16_to_f(u16 h){
    return __uint_as_float(((unsigned int)h) << 16);
}
__device__ inline f32x4 mfma16x16x32(bf16x8 a, bf16x8 b, f32x4 c){
    return __builtin_amdgcn_mfma_f32_16x16x32_bf16(a, b, c, 0, 0, 0);
}

struct Params {
    const float* tw; const float* fw;
    const int* labels; const int* qsize;
    const float* Xt; const float* Wt; const float* Xf; const float* Wf;
    const float* bt; const float* bfv;
    const float* Wc; const float* bc; const float* Wo; const float* bo;
    float* degT; float* degF; float* dsum; float* colsb;
    float* Yt; float* Yf; float* feats;
    u16* Aw_hi; u16* Aw_lo; u16* ZcT_hi; u16* ZcT_lo;
    float* Pt; float* Pf; float* Pe;
    float* out;
};

// ---- phase 1: vb in [0,1025): deg (0..511) + labels (512) + XW (513..1024) ----
__device__ inline void ph_deg_label_xw(int vb, char* smem, const Params& P){
    int t = threadIdx.x;
    if (vb < 512){
        int p = (vb & 7)*256 + t;
        if (p < NM1){
            int s0 = (vb >> 3)*32;
            float lowT=0.f, highT=0.f, lowF=0.f, highF=0.f;
            #pragma unroll 8
            for (int r = 0; r < 32; ++r){
                int s = s0 + r;
                float vt = P.tw[(size_t)s*NM1 + p];
                float vf = P.fw[(size_t)s*NM1 + p];
                if (s <= p){ highT += vt; highF += vf; }
                else       { lowT  += vt; lowF  += vf; }
            }
            atomicAdd(&P.degT[p],   lowT);
            atomicAdd(&P.degF[p],   lowF);
            atomicAdd(&P.degT[p+1], highT);
            atomicAdd(&P.degF[p+1], highF);
        }
    } else if (vb == 512){
        float* lc = (float*)smem;
        __syncthreads();
        if (t < NC) lc[t] = 0.f;
        __syncthreads();
        for (int i = t; i < N; i += 256){
            int l = P.labels[i];
            if (l >= 0 && l < NC) lc[l] = 1.f;
        }
        __syncthreads();
        if (t < NC) P.colsb[t] = lc[t];
    } else {
        int idx = vb - 513;
        const float* X = (idx & 256) ? P.Xf : P.Xt;
        const float* W = (idx & 256) ? P.Wf : P.Wt;
        float*       Y = (idx & 256) ? P.Yf : P.Yt;
        float* Ws = (float*)smem;          // DT*ET floats
        float* Xs = Ws + DT*ET;            // 8*DT floats
        __syncthreads();                   // guard smem reuse
        for (int j = t; j < DT*ET; j += 256) Ws[j] = W[j];
        int i0 = (idx & 255)*8;
        for (int j = t; j < 8*DT; j += 256) Xs[j] = X[(size_t)i0*DT + j];
        __syncthreads();
        int r = t >> 5, f = t & 31;
        const float* xr = Xs + r*DT;
        float acc = 0.f;
        #pragma unroll 8
        for (int d = 0; d < DT; ++d) acc += xr[d]*Ws[d*ET+f];
        Y[(size_t)(i0+r)*ET+f] = acc;
    }
}

// ---- phase 2: split-K ET aggregation, both graphs (wave-uniform split) ----
__device__ inline void ph_agg_et(int i0, int kc, char* smem, const Params& P){
    float* Ast = (float*)smem;         // 64*68 [k][i]
    float* Asf = Ast + 64*68;
    float* Zst = Asf + 64*68;          // 64*ET [k][f] scaled
    float* Zsf = Zst + 64*ET;
    int t = threadIdx.x;
    int k0 = kc*128;
    int g  = t >> 7;
    int tt = t & 127;
    int ig = tt >> 3, fg = tt & 7;
    int r0 = ig*4, c0 = fg*4;
    const float* As = g ? Asf : Ast;
    const float* Zs = g ? Zsf : Zst;
    float acc[4][4];
    #pragma unroll
    for (int u=0;u<4;++u)
        #pragma unroll
        for (int v=0;v<4;++v) acc[u][v]=0.f;

    for (int kt = 0; kt < 2; ++kt){
        int kb = k0 + kt*64;
        #pragma unroll
        for (int e = 0; e < 16; ++e){
            int id = t + e*256;            // 0..4095
            int k_l = id >> 6, i_l = id & 63;
            int k = kb + k_l;
            int gi = i0 + i_l;
            float vt, vf;
            if (gi == k){ vt = 0.f; vf = 0.f; }
            else {
                size_t base = (size_t)k*NM1 + gi - (gi > k ? 1 : 0);
                vt = P.tw[base]; vf = P.fw[base];
            }
            Ast[k_l*68 + i_l] = vt;
            Asf[k_l*68 + i_l] = vf;
        }
        #pragma unroll
        for (int e = 0; e < 2; ++e){
            int id = t + e*256;            // 0..511 float4 ids over 64x32
            int row = id >> 3;
            int c4  = (id & 7)*4;
            float rdT = rsqrtf(1.f + P.degT[kb+row]);
            float rdF = rsqrtf(1.f + P.degF[kb+row]);
            float4 yt = *(const float4*)&P.Yt[(size_t)(kb+row)*ET + c4];
            float4 yf = *(const float4*)&P.Yf[(size_t)(kb+row)*ET + c4];
            yt.x*=rdT; yt.y*=rdT; yt.z*=rdT; yt.w*=rdT;
            yf.x*=rdF; yf.y*=rdF; yf.z*=rdF; yf.w*=rdF;
            *(float4*)&Zst[row*ET + c4] = yt;
            *(float4*)&Zsf[row*ET + c4] = yf;
        }
        __syncthreads();
        for (int k = 0; k < 64; ++k){
            float4 a = *(const float4*)&As[k*68 + r0];
            float4 z = *(const float4*)&Zs[k*ET + c0];
            const float* ap = (const float*)&a;
            const float* zp = (const float*)&z;
            #pragma unroll
            for (int u = 0; u < 4; ++u)
                #pragma unroll
                for (int v = 0; v < 4; ++v)
                    acc[u][v] += ap[u]*zp[v];
        }
        __syncthreads();
    }
    float* Pp = g ? P.Pf : P.Pt;
    #pragma unroll
    for (int u = 0; u < 4; ++u){
        size_t ii = (size_t)(i0 + r0 + u);
        float4 o;
        float* po = (float*)&o;
        #pragma unroll
        for (int v = 0; v < 4; ++v) po[v]=acc[u][v];
        *(float4*)&Pp[(size_t)kc*(N*ET) + ii*ET + c0] = o;
    }
}

// ---- phase 3: reduce partials + self + scale + bias + lrelu + onehot ----
__device__ inline void ph_feats_epi(int vb, const Params& P){
    int idx = vb*256 + (int)threadIdx.x;   // over 2048*64
    int i = idx >> 6;
    int f = idx & 63;
    float s, rd, b;
    if (f < ET){
        rd = rsqrtf(1.f + P.degT[i]);
        s = rd*P.Yt[(size_t)i*ET + f];
        #pragma unroll
        for (int kc = 0; kc < KC_ET; ++kc) s += P.Pt[(size_t)kc*(N*ET) + (size_t)i*ET + f];
        b = P.bt[f];
    } else {
        int g = f - ET;
        rd = rsqrtf(1.f + P.degF[i]);
        s = rd*P.Yf[(size_t)i*ET + g];
        #pragma unroll
        for (int kc = 0; kc < KC_ET; ++kc) s += P.Pf[(size_t)kc*(N*ET) + (size_t)i*ET + g];
        b = P.bfv[g];
    }
    float v = rd*s + b;
    P.feats[(size_t)i*FS + f] = v > 0.f ? v : 0.01f*v;
    if (f < NC){
        int nsup = N - P.qsize[0];
        P.feats[(size_t)i*FS + 2*ET + f] = (i < nsup) ? P.colsb[f] : 0.f;
    }
}

// ---- phase 4: Aw split-bf16 planes + fused row-sum atomics into dsum ----
__device__ inline void ph_build_aw(int i0, int j0, char* smem, const Params& P){
    float* fiT = (float*)smem;      // [dim][row] 64*68
    float* fjT = fiT + 64*68;
    int t = threadIdx.x;
    __syncthreads();                // guard LDS reuse across iterations/phases
    {
        int row = t >> 2;
        int cb  = (t & 3)*16;
        const float4* si = (const float4*)(P.feats + (size_t)(i0+row)*FS + cb);
        const float4* sj = (const float4*)(P.feats + (size_t)(j0+row)*FS + cb);
        #pragma unroll
        for (int s = 0; s < 4; ++s){
            float4 v = si[s];
            float4 w = sj[s];
            int c = cb + s*4;
            fiT[(c+0)*68+row]=v.x; fiT[(c+1)*68+row]=v.y; fiT[(c+2)*68+row]=v.z; fiT[(c+3)*68+row]=v.w;
            fjT[(c+0)*68+row]=w.x; fjT[(c+1)*68+row]=w.y; fjT[(c+2)*68+row]=w.z; fjT[(c+3)*68+row]=w.w;
        }
    }
    __syncthreads();
    int tx = t & 15, ty = t >> 4;
    float acc[4][4];
    #pragma unroll
    for (int u=0;u<4;++u)
        #pragma unroll
        for (int v=0;v<4;++v) acc[u][v]=0.f;
    for (int d = 0; d < 64; ++d){
        float4 a4 = *(const float4*)&fiT[d*68 + ty*4];
        float4 b4 = *(const float4*)&fjT[d*68 + tx*4];
        const float* ap = (const float*)&a4;
        const float* bp = (const float*)&b4;
        #pragma unroll
        for (int u = 0; u < 4; ++u)
            #pragma unroll
            for (int v = 0; v < 4; ++v)
                acc[u][v] += fabsf(ap[u]-bp[v]);
    }
    #pragma unroll
    for (int u = 0; u < 4; ++u){
        int gi = i0 + ty*4 + u;
        float po[4];
        u16 hh[4], ll[4];
        #pragma unroll
        for (int v = 0; v < 4; ++v){
            int gj = j0 + tx*4 + v;
            float w = (gi==gj) ? 1.0f : 1.0f/(acc[u][v] + 1e-5f);
            po[v] = w;
            u16 h = bf16_rne(w);
            hh[v] = h;
            ll[v] = bf16_rne(w - bf16_to_f(h));
        }
        uint2 ph, pl;
        ph.x = (unsigned)hh[0] | ((unsigned)hh[1]<<16);
        ph.y = (unsigned)hh[2] | ((unsigned)hh[3]<<16);
        pl.x = (unsigned)ll[0] | ((unsigned)ll[1]<<16);
        pl.y = (unsigned)ll[2] | ((unsigned)ll[3]<<16);
        *(uint2*)&P.Aw_hi[(size_t)gi*N + j0 + tx*4] = ph;
        *(uint2*)&P.Aw_lo[(size_t)gi*N + j0 + tx*4] = pl;
        float rs = (po[0]+po[1]) + (po[2]+po[3]);
        rs += __shfl_xor(rs, 1);
        rs += __shfl_xor(rs, 2);
        rs += __shfl_xor(rs, 4);
        rs += __shfl_xor(rs, 8);
        if (tx == 0) atomicAdd(&P.dsum[gi], rs);
    }
}

// ---- phase 5: ZcT[f][k=i] = rsqrt(dsum)*(feats@Wc), split-bf16, transposed ----
__device__ inline void ph_featswc_stage(char* smem, const Params& P){
    float* Wcs = (float*)smem;
    int t = threadIdx.x;
    for (int idx = t; idx < FD*EC; idx += 256) Wcs[idx] = P.Wc[idx];
}
__device__ inline void ph_featswc(int vb, char* smem, const Params& P){
    float* Wcs = (float*)smem;          // FD*EC
    float* fr  = Wcs + FD*EC;           // [8][72]
    float* zb  = fr + 8*72;             // [128][12]
    int t = threadIdx.x;
    int i0 = vb*8;
    __syncthreads();                    // Wcs visible + fr/zb reuse guard
    for (int idx = t; idx < 8*FD; idx += 256){
        int r = idx / FD;
        int c = idx - r*FD;
        fr[r*72 + c] = P.feats[(size_t)(i0+r)*FS + c];
    }
    __syncthreads();
    int f  = t & 127;
    int rh = t >> 7;
    for (int rr = 0; rr < 4; ++rr){
        int r = rh*4 + rr;
        float acc = 0.f;
        #pragma unroll
        for (int d = 0; d < FD; ++d) acc += fr[r*72+d]*Wcs[d*EC+f];
        int i = i0 + r;
        zb[f*12 + r] = rsqrtf(P.dsum[i])*acc;
    }
    __syncthreads();
    int p = rh, f2 = f;
    float4 v0 = *(const float4*)&zb[f2*12 + 0];
    float4 v1 = *(const float4*)&zb[f2*12 + 4];
    float vv[8] = {v0.x, v0.y, v0.z, v0.w, v1.x, v1.y, v1.z, v1.w};
    u16 s[8];
    #pragma unroll
    for (int j = 0; j < 8; ++j){
        u16 h = bf16_rne(vv[j]);
        s[j] = p ? bf16_rne(vv[j] - bf16_to_f(h)) : h;
    }
    uint4 pk;
    pk.x = (unsigned)s[0] | ((unsigned)s[1]<<16);
    pk.y = (unsigned)s[2] | ((unsigned)s[3]<<16);
    pk.z = (unsigned)s[4] | ((unsigned)s[5]<<16);
    pk.w = (unsigned)s[6] | ((unsigned)s[7]<<16);
    u16* dst = p ? P.ZcT_lo : P.ZcT_hi;
    *(uint4*)&dst[(size_t)f2*N + i0] = pk;
}

// ---- phase 6: split-K EC GEMM via split-bf16 MFMA (verified round 1) ----
__device__ inline void ph_agg_ec(int ib, int kc, char* smem, const Params& P){
    u16* Ah = (u16*)smem;        // [i][k] 64*72
    u16* Al = Ah + 64*72;
    u16* Zh = Al + 64*72;        // [f][k] 128*72
    u16* Zl = Zh + 128*72;
    int t = threadIdx.x;
    int w  = t >> 6;
    int l  = t & 63;
    int lr = l & 15;
    int lg = l >> 4;
    int i0 = ib*64;
    int kb0 = kc*128;
    f32x4 acc[8];
    #pragma unroll
    for (int tt = 0; tt < 8; ++tt) acc[tt] = (f32x4){0.f, 0.f, 0.f, 0.f};

    for (int sub = 0; sub < 2; ++sub){
        int kbs = kb0 + sub*64;
        #pragma unroll
        for (int e = 0; e < 2; ++e){
            int id = t + e*256;
            int row = id >> 3, ch = (id & 7)*8;
            uint4 vh = *(const uint4*)&P.Aw_hi[(size_t)(i0+row)*N + kbs + ch];
            uint4 vl = *(const uint4*)&P.Aw_lo[(size_t)(i0+row)*N + kbs + ch];
            *(uint4*)&Ah[row*72 + ch] = vh;
            *(uint4*)&Al[row*72 + ch] = vl;
        }
        #pragma unroll
        for (int e = 0; e < 4; ++e){
            int id = t + e*256;
            int row = id >> 3, ch = (id & 7)*8;
            uint4 vh = *(const uint4*)&P.ZcT_hi[(size_t)row*N + kbs + ch];
            uint4 vl = *(const uint4*)&P.ZcT_lo[(size_t)row*N + kbs + ch];
            *(uint4*)&Zh[row*72 + ch] = vh;
            *(uint4*)&Zl[row*72 + ch] = vl;
        }
        __syncthreads();
        #pragma unroll
        for (int ks = 0; ks < 2; ++ks){
            int aoff = (w*16 + lr)*72 + ks*32 + lg*8;
            bf16x8 aH = *(const bf16x8*)&Ah[aoff];
            bf16x8 aL = *(const bf16x8*)&Al[aoff];
            #pragma unroll
            for (int tt = 0; tt < 8; ++tt){
                int zoff = (tt*16 + lr)*72 + ks*32 + lg*8;
                bf16x8 bH = *(const bf16x8*)&Zh[zoff];
                bf16x8 bL = *(const bf16x8*)&Zl[zoff];
                acc[tt] = mfma16x16x32(aH, bH, acc[tt]);
                acc[tt] = mfma16x16x32(aL, bH, acc[tt]);
                acc[tt] = mfma16x16x32(aH, bL, acc[tt]);
            }
        }
        __syncthreads();
    }
    float* pout = P.Pe + (size_t)kc*((size_t)N*EC);
    #pragma unroll
    for (int tt = 0; tt < 8; ++tt){
        #pragma unroll
        for (int r = 0; r < 4; ++r){
            int gi = i0 + w*16 + lg*4 + r;
            pout[(size_t)gi*EC + tt*16 + lr] = acc[tt][r];
        }
    }
}

// ---- phase 7: reduce Pe + scale + bias + lrelu -> emb -> out ----
__device__ inline void ph_embfinal_stage(char* smem, const Params& P){
    float* vs  = (float*)smem;
    float* Wos = vs + 2*EC;
    float* bos = Wos + EC*NC;
    int t = threadIdx.x;
    for (int idx = t; idx < EC*NC; idx += 256) Wos[idx] = P.Wo[idx];
    if (t < NC) bos[t] = P.bo[t];
}
__device__ inline void ph_embfinal(int vb, char* smem, const Params& P){
    float* vs  = (float*)smem;
    float* Wos = vs + 2*EC;
    float* bos = Wos + EC*NC;
    int t = threadIdx.x;
    __syncthreads();               // stage visible + vs reuse guard
    int rr = t >> 7, f = t & 127;
    int i = vb*2 + rr;
    size_t idx = (size_t)i*EC + f;
    float s = 0.f;
    #pragma unroll
    for (int kc = 0; kc < KC_EC; ++kc) s += P.Pe[(size_t)kc*(N*EC) + idx];
    float v = rsqrtf(P.dsum[i])*s + P.bc[f];
    vs[rr*EC + f] = v > 0.f ? v : 0.01f*v;
    __syncthreads();
    if (t < 2*NC){
        int r = t / NC;
        int c = t - r*NC;
        float a = bos[c];
        #pragma unroll 8
        for (int f2 = 0; f2 < EC; ++f2) a += vs[r*EC + f2]*Wos[f2*NC+c];
        P.out[(size_t)(vb*2 + r)*NC + c] = a;
    }
}

// ================= single cooperative mega-kernel =================
__global__ __launch_bounds__(256, 2) void kfull(Params P){
    __shared__ __align__(16) char smem[SMEM_MAX];
    cg::grid_group grid = cg::this_grid();
    int G = gridDim.x;
    int b = blockIdx.x;
    int t = threadIdx.x;

    // P0: zero degT/degF/dsum/colsb (contiguous 3N+8 floats)
    for (int idx = b*256 + t; idx < 3*N + 8; idx += G*256) P.degT[idx] = 0.f;
    grid.sync();
    // P1
    for (int vb = b; vb < 1025; vb += G) ph_deg_label_xw(vb, smem, P);
    grid.sync();
    // P2
    for (int vb = b; vb < 512; vb += G) ph_agg_et((vb & 31)*64, vb >> 5, smem, P);
    grid.sync();
    // P3
    for (int vb = b; vb < 512; vb += G) ph_feats_epi(vb, P);
    grid.sync();
    // P4
    for (int vb = b; vb < 1024; vb += G) ph_build_aw((vb & 31)*64, (vb >> 5)*64, smem, P);
    grid.sync();
    // P5
    ph_featswc_stage(smem, P);
    for (int vb = b; vb < 256; vb += G) ph_featswc(vb, smem, P);
    grid.sync();
    // P6
    for (int vb = b; vb < 512; vb += G) ph_agg_ec(vb & 31, vb >> 5, smem, P);
    grid.sync();
    // P7
    ph_embfinal_stage(smem, P);
    for (int vb = b; vb < 1024; vb += G) ph_embfinal(vb, smem, P);
}

// ================= fallback standalone kernels =================
__global__ __launch_bounds__(256) void k1s(Params P){
    __shared__ __align__(16) char s[(DT*ET + 8*DT)*4];
    ph_deg_label_xw(blockIdx.x, s, P);
}
__global__ __launch_bounds__(256) void k2s(Params P){
    __shared__ __align__(16) char s[(2*64*68 + 2*64*ET)*4];
    ph_agg_et(((int)blockIdx.x & 31)*64, (int)blockIdx.x >> 5, s, P);
}
__global__ __launch_bounds__(256) void k3s(Params P){ ph_feats_epi(blockIdx.x, P); }
__global__ __launch_bounds__(256) void k4s(Params P){
    __shared__ __align__(16) char s[2*64*68*4];
    ph_build_aw(((int)blockIdx.x & 31)*64, ((int)blockIdx.x >> 5)*64, s, P);
}
__global__ __launch_bounds__(256) void k5s(Params P){
    __shared__ __align__(16) char s[(FD*EC + 8*72 + 128*12)*4];
    ph_featswc_stage(s, P);
    ph_featswc(blockIdx.x, s, P);
}
__global__ __launch_bounds__(256) void k6s(Params P){
    __shared__ __align__(16) char s[SMEM_MAX];
    ph_agg_ec((int)blockIdx.x & 31, (int)blockIdx.x >> 5, s, P);
}
__global__ __launch_bounds__(256) void k7s(Params P){
    __shared__ __align__(16) char s[(2*EC + EC*NC + 8)*4];
    ph_embfinal_stage(s, P);
    ph_embfinal(blockIdx.x, s, P);
}

extern "C" void kernel_launch(void* const* d_in, const int* in_sizes, int n_in,
                              void* d_out, int out_size, void* d_ws, size_t ws_size,
                              hipStream_t stream) {
    Params P;
    P.Xt     = (const float*)d_in[0];
    P.tw     = (const float*)d_in[2];
    P.Xf     = (const float*)d_in[3];
    P.fw     = (const float*)d_in[4];
    P.labels = (const int*)d_in[5];
    P.qsize  = (const int*)d_in[7];
    P.Wt  = (const float*)d_in[8];
    P.bt  = (const float*)d_in[9];
    P.Wf  = (const float*)d_in[10];
    P.bfv = (const float*)d_in[11];
    P.Wc  = (const float*)d_in[12];
    P.bc  = (const float*)d_in[13];
    P.Wo  = (const float*)d_in[14];
    P.bo  = (const float*)d_in[15];
    P.out = (float*)d_out;

    float* ws    = (float*)d_ws;
    P.Yt    = ws;                           // N*ET
    P.Yf    = P.Yt + (size_t)N*ET;          // N*ET
    float* Zc = P.Yf + (size_t)N*ET;        // N*EC region (bf16 planes, transposed)
    P.degT  = Zc + (size_t)N*EC;            // N
    P.degF  = P.degT + N;                   // N
    P.dsum  = P.degF + N;                   // N
    P.colsb = P.dsum + N;                   // 8
    P.feats = P.colsb + 8;                  // N*FS
    float* Aw = P.feats + (size_t)N*FS;     // N*N region (bf16 planes)
    P.Pt    = Aw + (size_t)N*N;             // KC_ET*N*ET
    P.Pf    = P.Pt + (size_t)KC_ET*N*ET;    // KC_ET*N*ET
    P.Pe    = P.Pf + (size_t)KC_ET*N*ET;    // KC_EC*N*EC

    P.Aw_hi  = (u16*)Aw;
    P.Aw_lo  = P.Aw_hi + (size_t)N*N;
    P.ZcT_hi = (u16*)Zc;
    P.ZcT_lo = P.ZcT_hi + (size_t)N*EC;

    // cooperative grid size: 2 blocks/CU guaranteed by launch_bounds+LDS,
    // clamped by runtime occupancy query for safety.
    static int gmax = 0;
    if (gmax == 0){
        int nb = 0;
        if (hipOccupancyMaxActiveBlocksPerMultiprocessor(&nb, (const void*)kfull, 256, 0) != hipSuccess || nb < 1)
            nb = 2;
        int ncu = 0;
        hipDeviceProp_t prop;
        int dev = 0;
        if (hipGetDevice(&dev) == hipSuccess && hipGetDeviceProperties(&prop, dev) == hipSuccess)
            ncu = prop.multiProcessorCount;
        if (ncu <= 0) ncu = 256;
        long cap = (long)nb * (long)ncu;
        gmax = cap < 512 ? (int)cap : 512;
        if (gmax < 1) gmax = 1;
    }

    static int coop_ok = -1;
    if (coop_ok != 0){
        void* kargs[] = { (void*)&P };
        hipError_t e = hipLaunchCooperativeKernel((const void*)kfull, dim3(gmax), dim3(256),
                                                  kargs, 0, stream);
        if (e == hipSuccess){ coop_ok = 1; return; }
        coop_ok = 0;
        (void)hipGetLastError();
    }
    // fallback: original multi-dispatch path
    hipMemsetAsync(P.degT, 0, (3*N + 8)*sizeof(float), stream);
    k1s<<<1025, 256, 0, stream>>>(P);
    k2s<<<512, 256, 0, stream>>>(P);
    k3s<<<512, 256, 0, stream>>>(P);
    k4s<<<1024, 256, 0, stream>>>(P);
    k5s<<<256, 256, 0, stream>>>(P);
    k6s<<<512, 256, 0, stream>>>(P);
    k7s<<<1024, 256, 0, stream>>>(P);
}

// Round 5
// 264.583 us; speedup vs baseline: 1.7895x; 1.7895x over previous
//
#include <hip/hip_runtime.h>
#include <hip/hip_bf16.h>

#define N 2048
#define NM1 2047
#define DT 256
#define ET 32
#define EC 128
#define NC 5
#define FS 80    // feats row stride (floats)
#define FD 69    // used feature cols

typedef unsigned short u16;
typedef float f32x4 __attribute__((ext_vector_type(4)));
typedef __bf16 bf16x8 __attribute__((ext_vector_type(8)));

__device__ inline u16 bf16_rne(float x){
    unsigned int b = __float_as_uint(x);
    b += 0x7fffu + ((b >> 16) & 1u);
    return (u16)(b >> 16);
}
__device__ inline float bf16_to_f(u16 h){
    return __uint_as_float(((unsigned int)h) << 16);
}
__device__ inline f32x4 mfma16x16x32(bf16x8 a, bf16x8 b, f32x4 c){
    return __builtin_amdgcn_mfma_f32_16x16x32_bf16(a, b, c, 0, 0, 0);
}

// ==== k1: deg (blocks 0..511) + labels (512) + XW (513..1024) — round-1 verified ====
__global__ __launch_bounds__(256) void k_deg_label_xw(const float* __restrict__ tw,
                                                      const float* __restrict__ fw,
                                                      const int* __restrict__ labels,
                                                      const float* __restrict__ Xt,
                                                      const float* __restrict__ Wt,
                                                      const float* __restrict__ Xf,
                                                      const float* __restrict__ Wf,
                                                      float* __restrict__ degT,
                                                      float* __restrict__ degF,
                                                      float* __restrict__ cols,
                                                      float* __restrict__ Yt,
                                                      float* __restrict__ Yf){
    int b = blockIdx.x;
    int t = threadIdx.x;
    if (b < 512){
        int p = (b & 7)*256 + t;
        if (p >= NM1) return;
        int s0 = (b >> 3)*32;
        float lowT=0.f, highT=0.f, lowF=0.f, highF=0.f;
        #pragma unroll 8
        for (int r = 0; r < 32; ++r){
            int s = s0 + r;
            float vt = tw[(size_t)s*NM1 + p];
            float vf = fw[(size_t)s*NM1 + p];
            if (s <= p){ highT += vt; highF += vf; }
            else       { lowT  += vt; lowF  += vf; }
        }
        atomicAdd(&degT[p],   lowT);
        atomicAdd(&degF[p],   lowF);
        atomicAdd(&degT[p+1], highT);
        atomicAdd(&degF[p+1], highF);
        return;
    }
    if (b == 512){
        __shared__ float lc[NC];
        if (t < NC) lc[t] = 0.f;
        __syncthreads();
        for (int i = t; i < N; i += 256){
            int l = labels[i];
            if (l >= 0 && l < NC) lc[l] = 1.f;
        }
        __syncthreads();
        if (t < NC) cols[t] = lc[t];
        return;
    }
    int idx = b - 513;
    const float* X = (idx & 256) ? Xf : Xt;
    const float* W = (idx & 256) ? Wf : Wt;
    float*       Y = (idx & 256) ? Yf : Yt;
    __shared__ float Ws[DT*ET];
    __shared__ float Xs[8*DT];
    for (int j = t; j < DT*ET; j += 256) Ws[j] = W[j];
    int i0 = (idx & 255)*8;
    for (int j = t; j < 8*DT; j += 256) Xs[j] = X[(size_t)i0*DT + j];
    __syncthreads();
    int r = t >> 5, f = t & 31;
    const float* xr = Xs + r*DT;
    float acc = 0.f;
    #pragma unroll 8
    for (int d = 0; d < DT; ++d) acc += xr[d]*Ws[d*ET+f];
    Y[(size_t)(i0+r)*ET+f] = acc;
}

// ==== k2n: full-K ET aggregation (split-bf16 MFMA) + fused feats epilogue ====
// 256 blocks = 128 row-tiles x 2 graphs; 16 rows/block; K=2048 in 32 subs of 64.
// waves = (colfrag cf, k-half kp); final LDS reduce pairs (w, w+2); epilogue
// in-block (all deps are dispatch-prior). MFMA fragment pattern verified r1.
__global__ __launch_bounds__(256) void k_agg_et_full(const float* __restrict__ tw,
                                                     const float* __restrict__ fw,
                                                     const float* __restrict__ Yt,
                                                     const float* __restrict__ Yf,
                                                     const float* __restrict__ degT,
                                                     const float* __restrict__ degF,
                                                     const float* __restrict__ bt,
                                                     const float* __restrict__ bfv,
                                                     const float* __restrict__ cols,
                                                     const int* __restrict__ qsize,
                                                     float* __restrict__ feats){
    __shared__ u16 Ah[16*72], Al[16*72];   // [i][k] 2.25KB each
    __shared__ u16 Zh[32*72], Zl[32*72];   // [f][k] 4.5KB each
    __shared__ float red[256*4];           // cross-wave reduce (4KB)
    int t = threadIdx.x;
    int tile = blockIdx.x >> 1;
    int g = blockIdx.x & 1;
    int i0 = tile*16;
    const float* A   = g ? fw   : tw;
    const float* Y   = g ? Yf   : Yt;
    const float* deg = g ? degF : degT;
    int w = t >> 6, l = t & 63, lr = l & 15, lg = l >> 4;
    int cf = w & 1, kp = w >> 1;
    f32x4 acc = {0.f, 0.f, 0.f, 0.f};

    for (int sub = 0; sub < 32; ++sub){
        int kb = sub*64;
        // stage A-tile 16i x 64k: A[i][k] = tw[k*2047 + i - (i>k)], diag 0
        #pragma unroll
        for (int e = 0; e < 4; ++e){
            int id = t + e*256;
            int i_l = id & 15, k_l = id >> 4;
            int gi = i0 + i_l, k = kb + k_l;
            float v = 0.f;
            if (gi != k) v = A[(size_t)k*NM1 + gi - (gi > k ? 1 : 0)];
            u16 h = bf16_rne(v);
            Ah[i_l*72 + k_l] = h;
            Al[i_l*72 + k_l] = bf16_rne(v - bf16_to_f(h));
        }
        // stage Z-tile 64k x 32f, pre-scaled by rsqrt(1+deg[k])
        #pragma unroll
        for (int e = 0; e < 8; ++e){
            int id = t + e*256;
            int f = id & 31, k_l = id >> 5;
            float rd = rsqrtf(1.f + deg[kb + k_l]);
            float v = rd * Y[(size_t)(kb+k_l)*ET + f];
            u16 h = bf16_rne(v);
            Zh[f*72 + k_l] = h;
            Zl[f*72 + k_l] = bf16_rne(v - bf16_to_f(h));
        }
        __syncthreads();
        int aoff = lr*72 + kp*32 + lg*8;
        int boff = (cf*16 + lr)*72 + kp*32 + lg*8;
        bf16x8 aH = *(const bf16x8*)&Ah[aoff];
        bf16x8 aL = *(const bf16x8*)&Al[aoff];
        bf16x8 bH = *(const bf16x8*)&Zh[boff];
        bf16x8 bL = *(const bf16x8*)&Zl[boff];
        acc = mfma16x16x32(aH, bH, acc);
        acc = mfma16x16x32(aL, bH, acc);
        acc = mfma16x16x32(aH, bL, acc);
        __syncthreads();
    }
    // reduce the two k-halves: wave w (<2) += wave w+2
    *(f32x4*)&red[t*4] = acc;
    __syncthreads();
    if (w < 2){
        f32x4 o = *(const f32x4*)&red[(t+128)*4];
        int fl = cf*16 + lr;           // cf == w for w<2
        float bb = g ? bfv[fl] : bt[fl];
        #pragma unroll
        for (int j = 0; j < 4; ++j){
            int i = i0 + lg*4 + j;     // C/D: row=(lane>>4)*4+reg, col=lane&15
            float rd = rsqrtf(1.f + deg[i]);
            float s = rd*Y[(size_t)i*ET + fl] + acc[j] + o[j];
            float v = rd*s + bb;
            feats[(size_t)i*FS + g*ET + fl] = v > 0.f ? v : 0.01f*v;
        }
    }
    if (g == 0 && t < 16*NC){
        int r = t / NC, c = t - r*NC;
        int nsup = N - qsize[0];
        feats[(size_t)(i0+r)*FS + 2*ET + c] = (i0+r < nsup) ? cols[c] : 0.f;
    }
}

// ==== k3: Aw split-bf16 planes + dsum atomics — round-1 verified ====
__global__ __launch_bounds__(256) void k_build_aw(const float* __restrict__ feats,
                                                  u16* __restrict__ Aw_hi,
                                                  u16* __restrict__ Aw_lo,
                                                  float* __restrict__ dsum){
    __shared__ float fiT[64*68];   // [dim][row]
    __shared__ float fjT[64*68];
    int t = threadIdx.x;
    int i0 = blockIdx.x*64, j0 = blockIdx.y*64;
    {
        int row = t >> 2;
        int cb  = (t & 3)*16;
        const float4* si = (const float4*)(feats + (size_t)(i0+row)*FS + cb);
        const float4* sj = (const float4*)(feats + (size_t)(j0+row)*FS + cb);
        #pragma unroll
        for (int s = 0; s < 4; ++s){
            float4 v = si[s];
            float4 w = sj[s];
            int c = cb + s*4;
            fiT[(c+0)*68+row]=v.x; fiT[(c+1)*68+row]=v.y; fiT[(c+2)*68+row]=v.z; fiT[(c+3)*68+row]=v.w;
            fjT[(c+0)*68+row]=w.x; fjT[(c+1)*68+row]=w.y; fjT[(c+2)*68+row]=w.z; fjT[(c+3)*68+row]=w.w;
        }
    }
    __syncthreads();
    int tx = t & 15, ty = t >> 4;
    float acc[4][4];
    #pragma unroll
    for (int u=0;u<4;++u)
        #pragma unroll
        for (int v=0;v<4;++v) acc[u][v]=0.f;
    for (int d = 0; d < 64; ++d){
        float4 a4 = *(const float4*)&fiT[d*68 + ty*4];
        float4 b4 = *(const float4*)&fjT[d*68 + tx*4];
        const float* ap = (const float*)&a4;
        const float* bp = (const float*)&b4;
        #pragma unroll
        for (int u = 0; u < 4; ++u)
            #pragma unroll
            for (int v = 0; v < 4; ++v)
                acc[u][v] += fabsf(ap[u]-bp[v]);
    }
    #pragma unroll
    for (int u = 0; u < 4; ++u){
        int gi = i0 + ty*4 + u;
        float po[4];
        u16 hh[4], ll[4];
        #pragma unroll
        for (int v = 0; v < 4; ++v){
            int gj = j0 + tx*4 + v;
            float w = (gi==gj) ? 1.0f : 1.0f/(acc[u][v] + 1e-5f);
            po[v] = w;
            u16 h = bf16_rne(w);
            hh[v] = h;
            ll[v] = bf16_rne(w - bf16_to_f(h));
        }
        uint2 ph, pl;
        ph.x = (unsigned)hh[0] | ((unsigned)hh[1]<<16);
        ph.y = (unsigned)hh[2] | ((unsigned)hh[3]<<16);
        pl.x = (unsigned)ll[0] | ((unsigned)ll[1]<<16);
        pl.y = (unsigned)ll[2] | ((unsigned)ll[3]<<16);
        *(uint2*)&Aw_hi[(size_t)gi*N + j0 + tx*4] = ph;
        *(uint2*)&Aw_lo[(size_t)gi*N + j0 + tx*4] = pl;
        float rs = (po[0]+po[1]) + (po[2]+po[3]);
        rs += __shfl_xor(rs, 1);
        rs += __shfl_xor(rs, 2);
        rs += __shfl_xor(rs, 4);
        rs += __shfl_xor(rs, 8);
        if (tx == 0) atomicAdd(&dsum[gi], rs);
    }
}

// ==== k4: ZcT[f][k] = rsqrt(dsum)*(feats@Wc), split-bf16 transposed — r1 verified ====
__global__ __launch_bounds__(256) void k_featswc(const float* __restrict__ feats,
                                                 const float* __restrict__ Wc,
                                                 const float* __restrict__ dsum,
                                                 u16* __restrict__ ZcT_hi,
                                                 u16* __restrict__ ZcT_lo){
    __shared__ float Wcs[FD*EC];
    __shared__ float fr[8][FD+3];
    __shared__ float zb[128][12];
    int t = threadIdx.x; // 256
    for (int idx = t; idx < FD*EC; idx += 256) Wcs[idx] = Wc[idx];
    int i0 = blockIdx.x*8;
    for (int idx = t; idx < 8*FD; idx += 256){
        int r = idx / FD;
        int c = idx - r*FD;
        fr[r][c] = feats[(size_t)(i0+r)*FS + c];
    }
    __syncthreads();
    int f  = t & 127;
    int rh = t >> 7;
    for (int rr = 0; rr < 4; ++rr){
        int r = rh*4 + rr;
        float acc = 0.f;
        #pragma unroll
        for (int d = 0; d < FD; ++d) acc += fr[r][d]*Wcs[d*EC+f];
        int i = i0 + r;
        zb[f][r] = rsqrtf(dsum[i])*acc;
    }
    __syncthreads();
    int p = rh, f2 = f;
    float4 v0 = *(const float4*)&zb[f2][0];
    float4 v1 = *(const float4*)&zb[f2][4];
    float vv[8] = {v0.x, v0.y, v0.z, v0.w, v1.x, v1.y, v1.z, v1.w};
    u16 s[8];
    #pragma unroll
    for (int j = 0; j < 8; ++j){
        u16 h = bf16_rne(vv[j]);
        s[j] = p ? bf16_rne(vv[j] - bf16_to_f(h)) : h;
    }
    uint4 pk;
    pk.x = (unsigned)s[0] | ((unsigned)s[1]<<16);
    pk.y = (unsigned)s[2] | ((unsigned)s[3]<<16);
    pk.z = (unsigned)s[4] | ((unsigned)s[5]<<16);
    pk.w = (unsigned)s[6] | ((unsigned)s[7]<<16);
    u16* dst = p ? ZcT_lo : ZcT_hi;
    *(uint4*)&dst[(size_t)f2*N + i0] = pk;
}

// ==== k5n: full-K EC aggregation (split-bf16 MFMA) + fused embfinal ====
// 128 blocks x 16-row tiles; K=2048 in 32 subs; wave w owns colfrags 2w,2w+1
// (no cross-wave reduce); epilogue in-block. Aw HBM once; ZcT L2-resident.
__global__ __launch_bounds__(256) void k_agg_ec_full(const u16* __restrict__ Aw_hi,
                                                     const u16* __restrict__ Aw_lo,
                                                     const u16* __restrict__ ZcT_hi,
                                                     const u16* __restrict__ ZcT_lo,
                                                     const float* __restrict__ dsum,
                                                     const float* __restrict__ bc,
                                                     const float* __restrict__ Wo,
                                                     const float* __restrict__ bo,
                                                     float* __restrict__ out){
    __shared__ u16 Ah[16*72], Al[16*72];     // [i][k] 2.25KB each
    __shared__ u16 Zh[128*72], Zl[128*72];   // [f][k] 18KB each
    __shared__ float vs[16*128];             // emb tile (8KB)
    int t = threadIdx.x;
    int i0 = blockIdx.x*16;
    int w = t >> 6, l = t & 63, lr = l & 15, lg = l >> 4;
    f32x4 acc0 = {0.f,0.f,0.f,0.f}, acc1 = {0.f,0.f,0.f,0.f};

    for (int sub = 0; sub < 32; ++sub){
        int kb = sub*64;
        {
            int row = t >> 4, c4 = (t & 15)*4;
            *(uint2*)&Ah[row*72 + c4] = *(const uint2*)&Aw_hi[(size_t)(i0+row)*N + kb + c4];
            *(uint2*)&Al[row*72 + c4] = *(const uint2*)&Aw_lo[(size_t)(i0+row)*N + kb + c4];
        }
        #pragma unroll
        for (int e = 0; e < 4; ++e){
            int id = t + e*256;
            int fr = id >> 3, ch = (id & 7)*8;
            *(uint4*)&Zh[fr*72 + ch] = *(const uint4*)&ZcT_hi[(size_t)fr*N + kb + ch];
            *(uint4*)&Zl[fr*72 + ch] = *(const uint4*)&ZcT_lo[(size_t)fr*N + kb + ch];
        }
        __syncthreads();
        #pragma unroll
        for (int ks = 0; ks < 2; ++ks){
            int aoff = lr*72 + ks*32 + lg*8;
            bf16x8 aH = *(const bf16x8*)&Ah[aoff];
            bf16x8 aL = *(const bf16x8*)&Al[aoff];
            int b0 = ((w*2+0)*16 + lr)*72 + ks*32 + lg*8;
            int b1 = ((w*2+1)*16 + lr)*72 + ks*32 + lg*8;
            bf16x8 bH0 = *(const bf16x8*)&Zh[b0];
            bf16x8 bL0 = *(const bf16x8*)&Zl[b0];
            bf16x8 bH1 = *(const bf16x8*)&Zh[b1];
            bf16x8 bL1 = *(const bf16x8*)&Zl[b1];
            acc0 = mfma16x16x32(aH, bH0, acc0);
            acc0 = mfma16x16x32(aL, bH0, acc0);
            acc0 = mfma16x16x32(aH, bL0, acc0);
            acc1 = mfma16x16x32(aH, bH1, acc1);
            acc1 = mfma16x16x32(aL, bH1, acc1);
            acc1 = mfma16x16x32(aH, bL1, acc1);
        }
        __syncthreads();
    }
    // epilogue: emb = lrelu(rsqrt(dsum)*agg + bc) -> vs
    #pragma unroll
    for (int j = 0; j < 4; ++j){
        int row = lg*4 + j;
        float rdv = rsqrtf(dsum[i0+row]);
        int c0 = (w*2+0)*16 + lr;
        int c1 = (w*2+1)*16 + lr;
        float v0 = rdv*acc0[j] + bc[c0];
        float v1 = rdv*acc1[j] + bc[c1];
        vs[row*128 + c0] = v0 > 0.f ? v0 : 0.01f*v0;
        vs[row*128 + c1] = v1 > 0.f ? v1 : 0.01f*v1;
    }
    __syncthreads();
    if (t < 16*NC){
        int r = t / NC, c = t - r*NC;
        float a = bo[c];
        #pragma unroll 8
        for (int f = 0; f < EC; ++f) a += vs[r*128 + f]*Wo[f*NC + c];
        out[(size_t)(i0 + r)*NC + c] = a;
    }
}

extern "C" void kernel_launch(void* const* d_in, const int* in_sizes, int n_in,
                              void* d_out, int out_size, void* d_ws, size_t ws_size,
                              hipStream_t stream) {
    const float* time_features = (const float*)d_in[0];
    const float* tw            = (const float*)d_in[2];
    const float* freq_features = (const float*)d_in[3];
    const float* fw            = (const float*)d_in[4];
    const int*   labels        = (const int*)d_in[5];
    const int*   qsize         = (const int*)d_in[7];
    const float* Wt  = (const float*)d_in[8];
    const float* bt  = (const float*)d_in[9];
    const float* Wf  = (const float*)d_in[10];
    const float* bfv = (const float*)d_in[11];
    const float* Wc  = (const float*)d_in[12];
    const float* bc  = (const float*)d_in[13];
    const float* Wo  = (const float*)d_in[14];
    const float* bo  = (const float*)d_in[15];
    float* out = (float*)d_out;

    float* ws    = (float*)d_ws;
    float* degT  = ws;                         // N   (memset)
    float* degF  = degT + N;                   // N   (memset)
    float* dsum  = degF + N;                   // N   (memset)
    float* colsb = dsum + N;                   // 8
    float* Yt    = colsb + 8;                  // N*ET
    float* Yf    = Yt + (size_t)N*ET;          // N*ET
    float* feats = Yf + (size_t)N*ET;          // N*FS
    float* Zc    = feats + (size_t)N*FS;       // N*EC floats (2 bf16 planes)
    float* Aw    = Zc + (size_t)N*EC;          // N*N floats (2 bf16 planes)

    u16* ZcT_hi = (u16*)Zc;
    u16* ZcT_lo = ZcT_hi + (size_t)N*EC;
    u16* Aw_hi  = (u16*)Aw;
    u16* Aw_lo  = Aw_hi + (size_t)N*N;

    hipMemsetAsync(degT, 0, 3*N*sizeof(float), stream);
    k_deg_label_xw<<<1025, 256, 0, stream>>>(tw, fw, labels,
                                             time_features, Wt, freq_features, Wf,
                                             degT, degF, colsb, Yt, Yf);
    k_agg_et_full<<<256, 256, 0, stream>>>(tw, fw, Yt, Yf, degT, degF,
                                           bt, bfv, colsb, qsize, feats);
    k_build_aw<<<dim3(N/64, N/64), 256, 0, stream>>>(feats, Aw_hi, Aw_lo, dsum);
    k_featswc<<<N/8, 256, 0, stream>>>(feats, Wc, dsum, ZcT_hi, ZcT_lo);
    k_agg_ec_full<<<128, 256, 0, stream>>>(Aw_hi, Aw_lo, ZcT_hi, ZcT_lo,
                                           dsum, bc, Wo, bo, out);
}

// Round 6
// 231.443 us; speedup vs baseline: 2.0457x; 1.1432x over previous
//
#include <hip/hip_runtime.h>
#include <hip/hip_bf16.h>

#define N 2048
#define NM1 2047
#define DT 256
#define ET 32
#define EC 128
#define NC 5
#define FS 80    // feats row stride (floats)
#define FD 69    // used feature cols
#define KC_ET 16 // k-chunks for ET GEMMs (chunk = 128)
#define KC_EC 16 // k-chunks for EC GEMM (chunk = 128)

typedef unsigned short u16;
typedef float f32x4 __attribute__((ext_vector_type(4)));
typedef __bf16 bf16x8 __attribute__((ext_vector_type(8)));

__device__ inline u16 bf16_rne(float x){
    unsigned int b = __float_as_uint(x);
    b += 0x7fffu + ((b >> 16) & 1u);
    return (u16)(b >> 16);
}
__device__ inline float bf16_to_f(u16 h){
    return __uint_as_float(((unsigned int)h) << 16);
}
__device__ inline f32x4 mfma16x16x32(bf16x8 a, bf16x8 b, f32x4 c){
    return __builtin_amdgcn_mfma_f32_16x16x32_bf16(a, b, c, 0, 0, 0);
}

// ==== k1: deg (0..511) + labels (512) + XW (513..1024) — r1 verified ====
__global__ __launch_bounds__(256) void k_deg_label_xw(const float* __restrict__ tw,
                                                      const float* __restrict__ fw,
                                                      const int* __restrict__ labels,
                                                      const float* __restrict__ Xt,
                                                      const float* __restrict__ Wt,
                                                      const float* __restrict__ Xf,
                                                      const float* __restrict__ Wf,
                                                      float* __restrict__ degT,
                                                      float* __restrict__ degF,
                                                      float* __restrict__ cols,
                                                      float* __restrict__ Yt,
                                                      float* __restrict__ Yf){
    int b = blockIdx.x;
    int t = threadIdx.x;
    if (b < 512){
        int p = (b & 7)*256 + t;
        if (p >= NM1) return;
        int s0 = (b >> 3)*32;
        float lowT=0.f, highT=0.f, lowF=0.f, highF=0.f;
        #pragma unroll 8
        for (int r = 0; r < 32; ++r){
            int s = s0 + r;
            float vt = tw[(size_t)s*NM1 + p];
            float vf = fw[(size_t)s*NM1 + p];
            if (s <= p){ highT += vt; highF += vf; }
            else       { lowT  += vt; lowF  += vf; }
        }
        atomicAdd(&degT[p],   lowT);
        atomicAdd(&degF[p],   lowF);
        atomicAdd(&degT[p+1], highT);
        atomicAdd(&degF[p+1], highF);
        return;
    }
    if (b == 512){
        __shared__ float lc[NC];
        if (t < NC) lc[t] = 0.f;
        __syncthreads();
        for (int i = t; i < N; i += 256){
            int l = labels[i];
            if (l >= 0 && l < NC) lc[l] = 1.f;
        }
        __syncthreads();
        if (t < NC) cols[t] = lc[t];
        return;
    }
    int idx = b - 513;
    const float* X = (idx & 256) ? Xf : Xt;
    const float* W = (idx & 256) ? Wf : Wt;
    float*       Y = (idx & 256) ? Yf : Yt;
    __shared__ float Ws[DT*ET];
    __shared__ float Xs[8*DT];
    for (int j = t; j < DT*ET; j += 256) Ws[j] = W[j];
    int i0 = (idx & 255)*8;
    for (int j = t; j < 8*DT; j += 256) Xs[j] = X[(size_t)i0*DT + j];
    __syncthreads();
    int r = t >> 5, f = t & 31;
    const float* xr = Xs + r*DT;
    float acc = 0.f;
    #pragma unroll 8
    for (int d = 0; d < DT; ++d) acc += xr[d]*Ws[d*ET+f];
    Y[(size_t)(i0+r)*ET+f] = acc;
}

// ==== k2: split-K ET aggregation — r1 verified body; atomic Sg accumulate ====
__global__ __launch_bounds__(256) void k_agg_et(const float* __restrict__ tw,
                                                const float* __restrict__ fw,
                                                const float* __restrict__ Yt,
                                                const float* __restrict__ Yf,
                                                const float* __restrict__ degT,
                                                const float* __restrict__ degF,
                                                float* __restrict__ SgT,
                                                float* __restrict__ SgF){
    __shared__ float Ast[64*68];   // [k][i]
    __shared__ float Asf[64*68];
    __shared__ float Zst[64*ET];   // [k][f] scaled
    __shared__ float Zsf[64*ET];
    int t = threadIdx.x;
    int i0 = blockIdx.x*64;
    int kc = blockIdx.y;           // 0..15, chunk 128
    int k0 = kc*128;
    int g  = t >> 7;               // wave-uniform graph select
    int tt = t & 127;
    int ig = tt >> 3, fg = tt & 7;
    int r0 = ig*4, c0 = fg*4;
    const float* As = g ? Asf : Ast;
    const float* Zs = g ? Zsf : Zst;
    float acc[4][4];
    #pragma unroll
    for (int u=0;u<4;++u)
        #pragma unroll
        for (int v=0;v<4;++v) acc[u][v]=0.f;

    for (int kt = 0; kt < 2; ++kt){
        int kb = k0 + kt*64;
        #pragma unroll
        for (int e = 0; e < 16; ++e){
            int id = t + e*256;            // 0..4095
            int k_l = id >> 6, i_l = id & 63;
            int k = kb + k_l;
            int gi = i0 + i_l;
            float vt, vf;
            if (gi == k){ vt = 0.f; vf = 0.f; }
            else {
                size_t base = (size_t)k*NM1 + gi - (gi > k ? 1 : 0);
                vt = tw[base]; vf = fw[base];
            }
            Ast[k_l*68 + i_l] = vt;
            Asf[k_l*68 + i_l] = vf;
        }
        #pragma unroll
        for (int e = 0; e < 2; ++e){
            int id = t + e*256;            // 0..511 float4 ids over 64x32
            int row = id >> 3;
            int c4  = (id & 7)*4;
            float rdT = rsqrtf(1.f + degT[kb+row]);
            float rdF = rsqrtf(1.f + degF[kb+row]);
            float4 yt = *(const float4*)&Yt[(size_t)(kb+row)*ET + c4];
            float4 yf = *(const float4*)&Yf[(size_t)(kb+row)*ET + c4];
            yt.x*=rdT; yt.y*=rdT; yt.z*=rdT; yt.w*=rdT;
            yf.x*=rdF; yf.y*=rdF; yf.z*=rdF; yf.w*=rdF;
            *(float4*)&Zst[row*ET + c4] = yt;
            *(float4*)&Zsf[row*ET + c4] = yf;
        }
        __syncthreads();
        for (int k = 0; k < 64; ++k){
            float4 a = *(const float4*)&As[k*68 + r0];
            float4 z = *(const float4*)&Zs[k*ET + c0];
            const float* ap = (const float*)&a;
            const float* zp = (const float*)&z;
            #pragma unroll
            for (int u = 0; u < 4; ++u)
                #pragma unroll
                for (int v = 0; v < 4; ++v)
                    acc[u][v] += ap[u]*zp[v];
        }
        __syncthreads();
    }
    float* Sg = g ? SgF : SgT;
    #pragma unroll
    for (int u = 0; u < 4; ++u)
        #pragma unroll
        for (int v = 0; v < 4; ++v)
            atomicAdd(&Sg[(size_t)(i0 + r0 + u)*ET + c0 + v], acc[u][v]);
}

// ==== k3: feats epilogue (reads Sg once instead of 16 partials) ====
__global__ __launch_bounds__(256) void k_feats_epi(const float* __restrict__ SgT,
                                                   const float* __restrict__ SgF,
                                                   const float* __restrict__ Yt,
                                                   const float* __restrict__ Yf,
                                                   const float* __restrict__ degT,
                                                   const float* __restrict__ degF,
                                                   const float* __restrict__ bt,
                                                   const float* __restrict__ bfv,
                                                   const float* __restrict__ cols,
                                                   const int* __restrict__ qsize,
                                                   float* __restrict__ feats){
    int idx = blockIdx.x*256 + threadIdx.x;   // over 2048*64
    int i = idx >> 6;
    int f = idx & 63;
    float s, rd, b;
    if (f < ET){
        rd = rsqrtf(1.f + degT[i]);
        s = rd*Yt[(size_t)i*ET + f] + SgT[(size_t)i*ET + f];
        b = bt[f];
    } else {
        int g = f - ET;
        rd = rsqrtf(1.f + degF[i]);
        s = rd*Yf[(size_t)i*ET + g] + SgF[(size_t)i*ET + g];
        b = bfv[g];
    }
    float v = rd*s + b;
    feats[(size_t)i*FS + f] = v > 0.f ? v : 0.01f*v;
    if (f < NC){
        int nsup = N - qsize[0];
        feats[(size_t)i*FS + 2*ET + f] = (i < nsup) ? cols[f] : 0.f;
    }
}

// ==== k4: Aw split-bf16 planes + dsum atomics — r1 verified ====
__global__ __launch_bounds__(256) void k_build_aw(const float* __restrict__ feats,
                                                  u16* __restrict__ Aw_hi,
                                                  u16* __restrict__ Aw_lo,
                                                  float* __restrict__ dsum){
    __shared__ float fiT[64*68];   // [dim][row]
    __shared__ float fjT[64*68];
    int t = threadIdx.x;
    int i0 = blockIdx.x*64, j0 = blockIdx.y*64;
    {
        int row = t >> 2;
        int cb  = (t & 3)*16;
        const float4* si = (const float4*)(feats + (size_t)(i0+row)*FS + cb);
        const float4* sj = (const float4*)(feats + (size_t)(j0+row)*FS + cb);
        #pragma unroll
        for (int s = 0; s < 4; ++s){
            float4 v = si[s];
            float4 w = sj[s];
            int c = cb + s*4;
            fiT[(c+0)*68+row]=v.x; fiT[(c+1)*68+row]=v.y; fiT[(c+2)*68+row]=v.z; fiT[(c+3)*68+row]=v.w;
            fjT[(c+0)*68+row]=w.x; fjT[(c+1)*68+row]=w.y; fjT[(c+2)*68+row]=w.z; fjT[(c+3)*68+row]=w.w;
        }
    }
    __syncthreads();
    int tx = t & 15, ty = t >> 4;
    float acc[4][4];
    #pragma unroll
    for (int u=0;u<4;++u)
        #pragma unroll
        for (int v=0;v<4;++v) acc[u][v]=0.f;
    for (int d = 0; d < 64; ++d){
        float4 a4 = *(const float4*)&fiT[d*68 + ty*4];
        float4 b4 = *(const float4*)&fjT[d*68 + tx*4];
        const float* ap = (const float*)&a4;
        const float* bp = (const float*)&b4;
        #pragma unroll
        for (int u = 0; u < 4; ++u)
            #pragma unroll
            for (int v = 0; v < 4; ++v)
                acc[u][v] += fabsf(ap[u]-bp[v]);
    }
    #pragma unroll
    for (int u = 0; u < 4; ++u){
        int gi = i0 + ty*4 + u;
        float po[4];
        u16 hh[4], ll[4];
        #pragma unroll
        for (int v = 0; v < 4; ++v){
            int gj = j0 + tx*4 + v;
            float w = (gi==gj) ? 1.0f : 1.0f/(acc[u][v] + 1e-5f);
            po[v] = w;
            u16 h = bf16_rne(w);
            hh[v] = h;
            ll[v] = bf16_rne(w - bf16_to_f(h));
        }
        uint2 ph, pl;
        ph.x = (unsigned)hh[0] | ((unsigned)hh[1]<<16);
        ph.y = (unsigned)hh[2] | ((unsigned)hh[3]<<16);
        pl.x = (unsigned)ll[0] | ((unsigned)ll[1]<<16);
        pl.y = (unsigned)ll[2] | ((unsigned)ll[3]<<16);
        *(uint2*)&Aw_hi[(size_t)gi*N + j0 + tx*4] = ph;
        *(uint2*)&Aw_lo[(size_t)gi*N + j0 + tx*4] = pl;
        float rs = (po[0]+po[1]) + (po[2]+po[3]);
        rs += __shfl_xor(rs, 1);
        rs += __shfl_xor(rs, 2);
        rs += __shfl_xor(rs, 4);
        rs += __shfl_xor(rs, 8);
        if (tx == 0) atomicAdd(&dsum[gi], rs);
    }
}

// ==== k5: ZcT[f][k] = rsqrt(dsum)*(feats@Wc), split-bf16 transposed — r1 verified ====
__global__ __launch_bounds__(256) void k_featswc(const float* __restrict__ feats,
                                                 const float* __restrict__ Wc,
                                                 const float* __restrict__ dsum,
                                                 u16* __restrict__ ZcT_hi,
                                                 u16* __restrict__ ZcT_lo){
    __shared__ float Wcs[FD*EC];
    __shared__ float fr[8][FD+3];
    __shared__ float zb[128][12];
    int t = threadIdx.x; // 256
    for (int idx = t; idx < FD*EC; idx += 256) Wcs[idx] = Wc[idx];
    int i0 = blockIdx.x*8;
    for (int idx = t; idx < 8*FD; idx += 256){
        int r = idx / FD;
        int c = idx - r*FD;
        fr[r][c] = feats[(size_t)(i0+r)*FS + c];
    }
    __syncthreads();
    int f  = t & 127;
    int rh = t >> 7;
    for (int rr = 0; rr < 4; ++rr){
        int r = rh*4 + rr;
        float acc = 0.f;
        #pragma unroll
        for (int d = 0; d < FD; ++d) acc += fr[r][d]*Wcs[d*EC+f];
        int i = i0 + r;
        zb[f][r] = rsqrtf(dsum[i])*acc;
    }
    __syncthreads();
    int p = rh, f2 = f;
    float4 v0 = *(const float4*)&zb[f2][0];
    float4 v1 = *(const float4*)&zb[f2][4];
    float vv[8] = {v0.x, v0.y, v0.z, v0.w, v1.x, v1.y, v1.z, v1.w};
    u16 s[8];
    #pragma unroll
    for (int j = 0; j < 8; ++j){
        u16 h = bf16_rne(vv[j]);
        s[j] = p ? bf16_rne(vv[j] - bf16_to_f(h)) : h;
    }
    uint4 pk;
    pk.x = (unsigned)s[0] | ((unsigned)s[1]<<16);
    pk.y = (unsigned)s[2] | ((unsigned)s[3]<<16);
    pk.z = (unsigned)s[4] | ((unsigned)s[5]<<16);
    pk.w = (unsigned)s[6] | ((unsigned)s[7]<<16);
    u16* dst = p ? ZcT_lo : ZcT_hi;
    *(uint4*)&dst[(size_t)f2*N + i0] = pk;
}

// ==== k6: split-K EC GEMM via split-bf16 MFMA — r1 verified body; atomic Eacc ====
__global__ __launch_bounds__(256) void k_agg_ec(const u16* __restrict__ Aw_hi,
                                                const u16* __restrict__ Aw_lo,
                                                const u16* __restrict__ ZcT_hi,
                                                const u16* __restrict__ ZcT_lo,
                                                float* __restrict__ Eacc){
    __shared__ u16 Ah[64*72];    // [i][k] bf16, row stride 72
    __shared__ u16 Al[64*72];
    __shared__ u16 Zh[128*72];   // [f][k]
    __shared__ u16 Zl[128*72];
    int t = threadIdx.x;
    int w  = t >> 6;
    int l  = t & 63;
    int lr = l & 15;
    int lg = l >> 4;
    int i0 = blockIdx.x*64;
    int kb0 = blockIdx.y*128;
    f32x4 acc[8];
    #pragma unroll
    for (int tt = 0; tt < 8; ++tt) acc[tt] = (f32x4){0.f, 0.f, 0.f, 0.f};

    for (int sub = 0; sub < 2; ++sub){
        int kbs = kb0 + sub*64;
        #pragma unroll
        for (int e = 0; e < 2; ++e){
            int id = t + e*256;
            int row = id >> 3, ch = (id & 7)*8;
            uint4 vh = *(const uint4*)&Aw_hi[(size_t)(i0+row)*N + kbs + ch];
            uint4 vl = *(const uint4*)&Aw_lo[(size_t)(i0+row)*N + kbs + ch];
            *(uint4*)&Ah[row*72 + ch] = vh;
            *(uint4*)&Al[row*72 + ch] = vl;
        }
        #pragma unroll
        for (int e = 0; e < 4; ++e){
            int id = t + e*256;
            int row = id >> 3, ch = (id & 7)*8;
            uint4 vh = *(const uint4*)&ZcT_hi[(size_t)row*N + kbs + ch];
            uint4 vl = *(const uint4*)&ZcT_lo[(size_t)row*N + kbs + ch];
            *(uint4*)&Zh[row*72 + ch] = vh;
            *(uint4*)&Zl[row*72 + ch] = vl;
        }
        __syncthreads();
        #pragma unroll
        for (int ks = 0; ks < 2; ++ks){
            int aoff = (w*16 + lr)*72 + ks*32 + lg*8;
            bf16x8 aH = *(const bf16x8*)&Ah[aoff];
            bf16x8 aL = *(const bf16x8*)&Al[aoff];
            #pragma unroll
            for (int tt = 0; tt < 8; ++tt){
                int zoff = (tt*16 + lr)*72 + ks*32 + lg*8;
                bf16x8 bH = *(const bf16x8*)&Zh[zoff];
                bf16x8 bL = *(const bf16x8*)&Zl[zoff];
                acc[tt] = mfma16x16x32(aH, bH, acc[tt]);
                acc[tt] = mfma16x16x32(aL, bH, acc[tt]);
                acc[tt] = mfma16x16x32(aH, bL, acc[tt]);
            }
        }
        __syncthreads();
    }
    #pragma unroll
    for (int tt = 0; tt < 8; ++tt){
        #pragma unroll
        for (int r = 0; r < 4; ++r){
            int gi = i0 + w*16 + lg*4 + r;        // C/D: row=(lane>>4)*4+reg
            atomicAdd(&Eacc[(size_t)gi*EC + tt*16 + lr], acc[tt][r]);
        }
    }
}

// ==== k7: emb epilogue (reads Eacc once) + out ====
__global__ __launch_bounds__(256) void k_embfinal(const float* __restrict__ Eacc,
                                                  const float* __restrict__ dsum,
                                                  const float* __restrict__ bc,
                                                  const float* __restrict__ Wo,
                                                  const float* __restrict__ bo,
                                                  float* __restrict__ out){
    __shared__ float vs[2][EC];
    __shared__ float Wos[EC*NC];
    __shared__ float bos[NC];
    int t = threadIdx.x;
    for (int idx = t; idx < EC*NC; idx += 256) Wos[idx] = Wo[idx];
    if (t < NC) bos[t] = bo[t];
    int rr = t >> 7, f = t & 127;
    int i = blockIdx.x*2 + rr;
    float s = Eacc[(size_t)i*EC + f];
    float v = rsqrtf(dsum[i])*s + bc[f];
    vs[rr][f] = v > 0.f ? v : 0.01f*v;
    __syncthreads();
    if (t < 2*NC){
        int r = t / NC;
        int c = t - r*NC;
        float a = bos[c];
        #pragma unroll 8
        for (int f2 = 0; f2 < EC; ++f2) a += vs[r][f2]*Wos[f2*NC+c];
        out[(size_t)(blockIdx.x*2 + r)*NC + c] = a;
    }
}

extern "C" void kernel_launch(void* const* d_in, const int* in_sizes, int n_in,
                              void* d_out, int out_size, void* d_ws, size_t ws_size,
                              hipStream_t stream) {
    const float* time_features = (const float*)d_in[0];
    const float* tw            = (const float*)d_in[2];
    const float* freq_features = (const float*)d_in[3];
    const float* fw            = (const float*)d_in[4];
    const int*   labels        = (const int*)d_in[5];
    const int*   qsize         = (const int*)d_in[7];
    const float* Wt  = (const float*)d_in[8];
    const float* bt  = (const float*)d_in[9];
    const float* Wf  = (const float*)d_in[10];
    const float* bfv = (const float*)d_in[11];
    const float* Wc  = (const float*)d_in[12];
    const float* bc  = (const float*)d_in[13];
    const float* Wo  = (const float*)d_in[14];
    const float* bo  = (const float*)d_in[15];
    float* out = (float*)d_out;

    float* ws    = (float*)d_ws;
    // one contiguous zero region: degT,degF,dsum,SgT,SgF,Eacc
    float* degT  = ws;                         // N
    float* degF  = degT + N;                   // N
    float* dsum  = degF + N;                   // N
    float* SgT   = dsum + N;                   // N*ET
    float* SgF   = SgT + (size_t)N*ET;         // N*ET
    float* Eacc  = SgF + (size_t)N*ET;         // N*EC
    float* colsb = Eacc + (size_t)N*EC;        // 8
    float* Yt    = colsb + 8;                  // N*ET
    float* Yf    = Yt + (size_t)N*ET;          // N*ET
    float* feats = Yf + (size_t)N*ET;          // N*FS
    float* Zc    = feats + (size_t)N*FS;       // N*EC floats (2 bf16 planes)
    float* Aw    = Zc + (size_t)N*EC;          // N*N floats (2 bf16 planes)

    u16* ZcT_hi = (u16*)Zc;
    u16* ZcT_lo = ZcT_hi + (size_t)N*EC;
    u16* Aw_hi  = (u16*)Aw;
    u16* Aw_lo  = Aw_hi + (size_t)N*N;

    size_t zbytes = ((size_t)3*N + 2*(size_t)N*ET + (size_t)N*EC)*sizeof(float);
    hipMemsetAsync(degT, 0, zbytes, stream);
    k_deg_label_xw<<<1025, 256, 0, stream>>>(tw, fw, labels,
                                             time_features, Wt, freq_features, Wf,
                                             degT, degF, colsb, Yt, Yf);
    k_agg_et<<<dim3(N/64, KC_ET), 256, 0, stream>>>(tw, fw, Yt, Yf, degT, degF, SgT, SgF);
    k_feats_epi<<<(N*64)/256, 256, 0, stream>>>(SgT, SgF, Yt, Yf, degT, degF,
                                                bt, bfv, colsb, qsize, feats);
    k_build_aw<<<dim3(N/64, N/64), 256, 0, stream>>>(feats, Aw_hi, Aw_lo, dsum);
    k_featswc<<<N/8, 256, 0, stream>>>(feats, Wc, dsum, ZcT_hi, ZcT_lo);
    k_agg_ec<<<dim3(N/64, KC_EC), 256, 0, stream>>>(Aw_hi, Aw_lo, ZcT_hi, ZcT_lo, Eacc);
    k_embfinal<<<N/2, 256, 0, stream>>>(Eacc, dsum, bc, Wo, bo, out);
}

// Round 7
// 191.062 us; speedup vs baseline: 2.4781x; 1.2114x over previous
//
#include <hip/hip_runtime.h>
#include <hip/hip_bf16.h>

#define N 2048
#define NM1 2047
#define DT 256
#define ET 32
#define EC 128
#define NC 5
#define FS 80    // feats row stride (floats)
#define FD 69    // used feature cols
#define KC_ET 16 // k-chunks for ET GEMMs (chunk = 128)
#define KC_EC 16 // k-chunks for EC GEMM (chunk = 128)

typedef unsigned short u16;
typedef float f32x4 __attribute__((ext_vector_type(4)));
typedef __bf16 bf16x8 __attribute__((ext_vector_type(8)));

__device__ inline u16 bf16_rne(float x){
    unsigned int b = __float_as_uint(x);
    b += 0x7fffu + ((b >> 16) & 1u);
    return (u16)(b >> 16);
}
__device__ inline float bf16_to_f(u16 h){
    return __uint_as_float(((unsigned int)h) << 16);
}
__device__ inline f32x4 mfma16x16x32(bf16x8 a, bf16x8 b, f32x4 c){
    return __builtin_amdgcn_mfma_f32_16x16x32_bf16(a, b, c, 0, 0, 0);
}

// ==== k1: deg (0..511) + labels (512) + XW (513..1024) — r1 verified ====
__global__ __launch_bounds__(256) void k_deg_label_xw(const float* __restrict__ tw,
                                                      const float* __restrict__ fw,
                                                      const int* __restrict__ labels,
                                                      const float* __restrict__ Xt,
                                                      const float* __restrict__ Wt,
                                                      const float* __restrict__ Xf,
                                                      const float* __restrict__ Wf,
                                                      float* __restrict__ degT,
                                                      float* __restrict__ degF,
                                                      float* __restrict__ cols,
                                                      float* __restrict__ Yt,
                                                      float* __restrict__ Yf){
    int b = blockIdx.x;
    int t = threadIdx.x;
    if (b < 512){
        int p = (b & 7)*256 + t;
        if (p >= NM1) return;
        int s0 = (b >> 3)*32;
        float lowT=0.f, highT=0.f, lowF=0.f, highF=0.f;
        #pragma unroll 8
        for (int r = 0; r < 32; ++r){
            int s = s0 + r;
            float vt = tw[(size_t)s*NM1 + p];
            float vf = fw[(size_t)s*NM1 + p];
            if (s <= p){ highT += vt; highF += vf; }
            else       { lowT  += vt; lowF  += vf; }
        }
        atomicAdd(&degT[p],   lowT);
        atomicAdd(&degF[p],   lowF);
        atomicAdd(&degT[p+1], highT);
        atomicAdd(&degF[p+1], highF);
        return;
    }
    if (b == 512){
        __shared__ float lc[NC];
        if (t < NC) lc[t] = 0.f;
        __syncthreads();
        for (int i = t; i < N; i += 256){
            int l = labels[i];
            if (l >= 0 && l < NC) lc[l] = 1.f;
        }
        __syncthreads();
        if (t < NC) cols[t] = lc[t];
        return;
    }
    int idx = b - 513;
    const float* X = (idx & 256) ? Xf : Xt;
    const float* W = (idx & 256) ? Wf : Wt;
    float*       Y = (idx & 256) ? Yf : Yt;
    __shared__ float Ws[DT*ET];
    __shared__ float Xs[8*DT];
    for (int j = t; j < DT*ET; j += 256) Ws[j] = W[j];
    int i0 = (idx & 255)*8;
    for (int j = t; j < 8*DT; j += 256) Xs[j] = X[(size_t)i0*DT + j];
    __syncthreads();
    int r = t >> 5, f = t & 31;
    const float* xr = Xs + r*DT;
    float acc = 0.f;
    #pragma unroll 8
    for (int d = 0; d < DT; ++d) acc += xr[d]*Ws[d*ET+f];
    Y[(size_t)(i0+r)*ET+f] = acc;
}

// ==== k2: split-K ET aggregation via split-bf16 MFMA ====
// grid (32,16): 64-row i-tiles x 128-k chunks. 4 waves: waves 0-1 graph T,
// 2-3 graph F; wave-half owns 32 rows. A-fragments built in registers from
// coalesced global loads (no LDS, no k-loop barriers); Z ([f][k], scaled)
// staged once per block. Fragment pattern + C/D mapping verified in r1 k6.
__global__ __launch_bounds__(256) void k_agg_et_m(const float* __restrict__ tw,
                                                  const float* __restrict__ fw,
                                                  const float* __restrict__ Yt,
                                                  const float* __restrict__ Yf,
                                                  const float* __restrict__ degT,
                                                  const float* __restrict__ degF,
                                                  float* __restrict__ Pt,
                                                  float* __restrict__ Pf){
    __shared__ u16 Zs[2][2][32][136];   // [graph][plane][f][k] 34816 B
    int t = threadIdx.x;
    int w = t >> 6, l = t & 63, lr = l & 15, lg = l >> 4;
    int g = w >> 1, wh = w & 1;
    int i0 = blockIdx.x*64;
    int kc = blockIdx.y;
    int k0 = kc*128;

    // stage Z for both graphs: thread t -> f = t>>3 (0..31), 16 consecutive k
    {
        int f = t >> 3;
        int kb16 = (t & 7)*16;
        #pragma unroll
        for (int gg = 0; gg < 2; ++gg){
            const float* Y   = gg ? Yf   : Yt;
            const float* deg = gg ? degF : degT;
            u16 h8[16], l8[16];
            #pragma unroll
            for (int j = 0; j < 16; ++j){
                int k = k0 + kb16 + j;
                float rd = rsqrtf(1.f + deg[k]);
                float v = rd * Y[(size_t)k*ET + f];
                u16 h = bf16_rne(v);
                h8[j] = h;
                l8[j] = bf16_rne(v - bf16_to_f(h));
            }
            uint4 pk;
            pk.x = (unsigned)h8[0] | ((unsigned)h8[1]<<16);
            pk.y = (unsigned)h8[2] | ((unsigned)h8[3]<<16);
            pk.z = (unsigned)h8[4] | ((unsigned)h8[5]<<16);
            pk.w = (unsigned)h8[6] | ((unsigned)h8[7]<<16);
            *(uint4*)&Zs[gg][0][f][kb16] = pk;
            pk.x = (unsigned)h8[8] | ((unsigned)h8[9]<<16);
            pk.y = (unsigned)h8[10] | ((unsigned)h8[11]<<16);
            pk.z = (unsigned)h8[12] | ((unsigned)h8[13]<<16);
            pk.w = (unsigned)h8[14] | ((unsigned)h8[15]<<16);
            *(uint4*)&Zs[gg][0][f][kb16+8] = pk;
            pk.x = (unsigned)l8[0] | ((unsigned)l8[1]<<16);
            pk.y = (unsigned)l8[2] | ((unsigned)l8[3]<<16);
            pk.z = (unsigned)l8[4] | ((unsigned)l8[5]<<16);
            pk.w = (unsigned)l8[6] | ((unsigned)l8[7]<<16);
            *(uint4*)&Zs[gg][1][f][kb16] = pk;
            pk.x = (unsigned)l8[8] | ((unsigned)l8[9]<<16);
            pk.y = (unsigned)l8[10] | ((unsigned)l8[11]<<16);
            pk.z = (unsigned)l8[12] | ((unsigned)l8[13]<<16);
            pk.w = (unsigned)l8[14] | ((unsigned)l8[15]<<16);
            *(uint4*)&Zs[gg][1][f][kb16+8] = pk;
        }
    }
    __syncthreads();

    const float* A = g ? fw : tw;
    f32x4 acc[2][2];
    #pragma unroll
    for (int fi = 0; fi < 2; ++fi)
        #pragma unroll
        for (int ff = 0; ff < 2; ++ff) acc[fi][ff] = (f32x4){0.f,0.f,0.f,0.f};

    for (int sub = 0; sub < 2; ++sub){
        int kb = k0 + sub*64;
        #pragma unroll
        for (int fi = 0; fi < 2; ++fi){
            int row = i0 + wh*32 + fi*16 + lr;
            #pragma unroll
            for (int ks = 0; ks < 2; ++ks){
                int kbase = kb + ks*32 + lg*8;
                u16 ah[8], al[8];
                #pragma unroll
                for (int j = 0; j < 8; ++j){
                    int k = kbase + j;
                    float v = 0.f;
                    if (row != k) v = A[(size_t)k*NM1 + row - (row > k ? 1 : 0)];
                    u16 h = bf16_rne(v);
                    ah[j] = h;
                    al[j] = bf16_rne(v - bf16_to_f(h));
                }
                uint4 pa, pb;
                pa.x = (unsigned)ah[0] | ((unsigned)ah[1]<<16);
                pa.y = (unsigned)ah[2] | ((unsigned)ah[3]<<16);
                pa.z = (unsigned)ah[4] | ((unsigned)ah[5]<<16);
                pa.w = (unsigned)ah[6] | ((unsigned)ah[7]<<16);
                pb.x = (unsigned)al[0] | ((unsigned)al[1]<<16);
                pb.y = (unsigned)al[2] | ((unsigned)al[3]<<16);
                pb.z = (unsigned)al[4] | ((unsigned)al[5]<<16);
                pb.w = (unsigned)al[6] | ((unsigned)al[7]<<16);
                bf16x8 aH = *(bf16x8*)&pa;
                bf16x8 aL = *(bf16x8*)&pb;
                int koff = sub*64 + ks*32 + lg*8;
                #pragma unroll
                for (int ff = 0; ff < 2; ++ff){
                    bf16x8 bH = *(const bf16x8*)&Zs[g][0][ff*16+lr][koff];
                    bf16x8 bL = *(const bf16x8*)&Zs[g][1][ff*16+lr][koff];
                    acc[fi][ff] = mfma16x16x32(aH, bH, acc[fi][ff]);
                    acc[fi][ff] = mfma16x16x32(aL, bH, acc[fi][ff]);
                    acc[fi][ff] = mfma16x16x32(aH, bL, acc[fi][ff]);
                }
            }
        }
    }
    float* P = g ? Pf : Pt;
    #pragma unroll
    for (int fi = 0; fi < 2; ++fi)
        #pragma unroll
        for (int ff = 0; ff < 2; ++ff)
            #pragma unroll
            for (int r = 0; r < 4; ++r){
                int gi = i0 + wh*32 + fi*16 + lg*4 + r;   // row=(lane>>4)*4+reg
                P[(size_t)kc*(N*ET) + (size_t)gi*ET + ff*16 + lr] = acc[fi][ff][r];
            }
}

// ==== k3: reduce partials + self term + scale + bias + lrelu + onehot — r1 verified ====
__global__ __launch_bounds__(256) void k_feats_epi(const float* __restrict__ Pt,
                                                   const float* __restrict__ Pf,
                                                   const float* __restrict__ Yt,
                                                   const float* __restrict__ Yf,
                                                   const float* __restrict__ degT,
                                                   const float* __restrict__ degF,
                                                   const float* __restrict__ bt,
                                                   const float* __restrict__ bfv,
                                                   const float* __restrict__ cols,
                                                   const int* __restrict__ qsize,
                                                   float* __restrict__ feats){
    int idx = blockIdx.x*256 + threadIdx.x;   // over 2048*64
    int i = idx >> 6;
    int f = idx & 63;
    float s, rd, b;
    if (f < ET){
        rd = rsqrtf(1.f + degT[i]);
        s = rd*Yt[(size_t)i*ET + f];
        #pragma unroll
        for (int kc = 0; kc < KC_ET; ++kc) s += Pt[(size_t)kc*(N*ET) + (size_t)i*ET + f];
        b = bt[f];
    } else {
        int g = f - ET;
        rd = rsqrtf(1.f + degF[i]);
        s = rd*Yf[(size_t)i*ET + g];
        #pragma unroll
        for (int kc = 0; kc < KC_ET; ++kc) s += Pf[(size_t)kc*(N*ET) + (size_t)i*ET + g];
        b = bfv[g];
    }
    float v = rd*s + b;
    feats[(size_t)i*FS + f] = v > 0.f ? v : 0.01f*v;
    if (f < NC){
        int nsup = N - qsize[0];
        feats[(size_t)i*FS + 2*ET + f] = (i < nsup) ? cols[f] : 0.f;
    }
}

// ==== k4: merged dispatch — blocks <1024: build_aw (r1 body); >=1024: featswc
// (UNSCALED: dis[k] moved to k_agg_ec A-staging). Both read only feats. ====
__global__ __launch_bounds__(256) void k_aw_zc(const float* __restrict__ feats,
                                               const float* __restrict__ Wc,
                                               u16* __restrict__ Aw_hi,
                                               u16* __restrict__ Aw_lo,
                                               u16* __restrict__ ZcT_hi,
                                               u16* __restrict__ ZcT_lo,
                                               float* __restrict__ dsum){
    __shared__ __align__(16) char sm[37632];
    int t = threadIdx.x;
    int b = blockIdx.x;
    if (b < 1024){
        float* fiT = (float*)sm;        // [dim][row] 64*68
        float* fjT = fiT + 64*68;
        int i0 = (b & 31)*64, j0 = (b >> 5)*64;
        {
            int row = t >> 2;
            int cb  = (t & 3)*16;
            const float4* si = (const float4*)(feats + (size_t)(i0+row)*FS + cb);
            const float4* sj = (const float4*)(feats + (size_t)(j0+row)*FS + cb);
            #pragma unroll
            for (int s = 0; s < 4; ++s){
                float4 v = si[s];
                float4 w = sj[s];
                int c = cb + s*4;
                fiT[(c+0)*68+row]=v.x; fiT[(c+1)*68+row]=v.y; fiT[(c+2)*68+row]=v.z; fiT[(c+3)*68+row]=v.w;
                fjT[(c+0)*68+row]=w.x; fjT[(c+1)*68+row]=w.y; fjT[(c+2)*68+row]=w.z; fjT[(c+3)*68+row]=w.w;
            }
        }
        __syncthreads();
        int tx = t & 15, ty = t >> 4;
        float acc[4][4];
        #pragma unroll
        for (int u=0;u<4;++u)
            #pragma unroll
            for (int v=0;v<4;++v) acc[u][v]=0.f;
        for (int d = 0; d < 64; ++d){
            float4 a4 = *(const float4*)&fiT[d*68 + ty*4];
            float4 b4 = *(const float4*)&fjT[d*68 + tx*4];
            const float* ap = (const float*)&a4;
            const float* bp = (const float*)&b4;
            #pragma unroll
            for (int u = 0; u < 4; ++u)
                #pragma unroll
                for (int v = 0; v < 4; ++v)
                    acc[u][v] += fabsf(ap[u]-bp[v]);
        }
        #pragma unroll
        for (int u = 0; u < 4; ++u){
            int gi = i0 + ty*4 + u;
            float po[4];
            u16 hh[4], ll[4];
            #pragma unroll
            for (int v = 0; v < 4; ++v){
                int gj = j0 + tx*4 + v;
                float w = (gi==gj) ? 1.0f : 1.0f/(acc[u][v] + 1e-5f);
                po[v] = w;
                u16 h = bf16_rne(w);
                hh[v] = h;
                ll[v] = bf16_rne(w - bf16_to_f(h));
            }
            uint2 ph, pl;
            ph.x = (unsigned)hh[0] | ((unsigned)hh[1]<<16);
            ph.y = (unsigned)hh[2] | ((unsigned)hh[3]<<16);
            pl.x = (unsigned)ll[0] | ((unsigned)ll[1]<<16);
            pl.y = (unsigned)ll[2] | ((unsigned)ll[3]<<16);
            *(uint2*)&Aw_hi[(size_t)gi*N + j0 + tx*4] = ph;
            *(uint2*)&Aw_lo[(size_t)gi*N + j0 + tx*4] = pl;
            float rs = (po[0]+po[1]) + (po[2]+po[3]);
            rs += __shfl_xor(rs, 1);
            rs += __shfl_xor(rs, 2);
            rs += __shfl_xor(rs, 4);
            rs += __shfl_xor(rs, 8);
            if (tx == 0) atomicAdd(&dsum[gi], rs);
        }
        return;
    }
    // featswc (unscaled), idx 0..255
    {
        float* Wcs = (float*)sm;          // FD*EC
        float* fr  = Wcs + FD*EC;         // [8][72]
        int idx = b - 1024;
        int i0 = idx*8;
        for (int j = t; j < FD*EC; j += 256) Wcs[j] = Wc[j];
        for (int j = t; j < 8*FD; j += 256){
            int r = j / FD;
            int c = j - r*FD;
            fr[r*72 + c] = feats[(size_t)(i0+r)*FS + c];
        }
        __syncthreads();
        int f  = t & 127;
        int rh = t >> 7;                  // rows rh*4 .. rh*4+3
        u16 hh[4], ll[4];
        #pragma unroll
        for (int rr = 0; rr < 4; ++rr){
            int r = rh*4 + rr;
            float acc = 0.f;
            #pragma unroll
            for (int d = 0; d < FD; ++d) acc += fr[r*72+d]*Wcs[d*EC+f];
            u16 h = bf16_rne(acc);
            hh[rr] = h;
            ll[rr] = bf16_rne(acc - bf16_to_f(h));
        }
        uint2 ph, pl;
        ph.x = (unsigned)hh[0] | ((unsigned)hh[1]<<16);
        ph.y = (unsigned)hh[2] | ((unsigned)hh[3]<<16);
        pl.x = (unsigned)ll[0] | ((unsigned)ll[1]<<16);
        pl.y = (unsigned)ll[2] | ((unsigned)ll[3]<<16);
        *(uint2*)&ZcT_hi[(size_t)f*N + i0 + rh*4] = ph;
        *(uint2*)&ZcT_lo[(size_t)f*N + i0 + rh*4] = pl;
    }
}

// ==== k5: split-K EC GEMM (r1-verified body); A scaled by rsqrt(dsum[k]) at stage ====
__global__ __launch_bounds__(256) void k_agg_ec(const u16* __restrict__ Aw_hi,
                                                const u16* __restrict__ Aw_lo,
                                                const u16* __restrict__ ZcT_hi,
                                                const u16* __restrict__ ZcT_lo,
                                                const float* __restrict__ dsum,
                                                float* __restrict__ Pe){
    __shared__ u16 Ah[64*72];    // [i][k]
    __shared__ u16 Al[64*72];
    __shared__ u16 Zh[128*72];   // [f][k]
    __shared__ u16 Zl[128*72];
    int t = threadIdx.x;
    int w  = t >> 6;
    int l  = t & 63;
    int lr = l & 15;
    int lg = l >> 4;
    int i0 = blockIdx.x*64;
    int kb0 = blockIdx.y*128;
    f32x4 acc[8];
    #pragma unroll
    for (int tt = 0; tt < 8; ++tt) acc[tt] = (f32x4){0.f, 0.f, 0.f, 0.f};

    for (int sub = 0; sub < 2; ++sub){
        int kbs = kb0 + sub*64;
        #pragma unroll
        for (int e = 0; e < 2; ++e){
            int id = t + e*256;
            int row = id >> 3, ch = (id & 7)*8;
            uint4 vh = *(const uint4*)&Aw_hi[(size_t)(i0+row)*N + kbs + ch];
            uint4 vl = *(const uint4*)&Aw_lo[(size_t)(i0+row)*N + kbs + ch];
            // apply dis[k] = rsqrt(dsum[k]): recombine, scale, resplit
            const u16* ph = (const u16*)&vh;
            const u16* pl = (const u16*)&vl;
            u16 nh[8], nl[8];
            #pragma unroll
            for (int j = 0; j < 8; ++j){
                float a = bf16_to_f(ph[j]) + bf16_to_f(pl[j]);
                float v = a * rsqrtf(dsum[kbs + ch + j]);
                u16 h = bf16_rne(v);
                nh[j] = h;
                nl[j] = bf16_rne(v - bf16_to_f(h));
            }
            uint4 oh, ol;
            oh.x = (unsigned)nh[0] | ((unsigned)nh[1]<<16);
            oh.y = (unsigned)nh[2] | ((unsigned)nh[3]<<16);
            oh.z = (unsigned)nh[4] | ((unsigned)nh[5]<<16);
            oh.w = (unsigned)nh[6] | ((unsigned)nh[7]<<16);
            ol.x = (unsigned)nl[0] | ((unsigned)nl[1]<<16);
            ol.y = (unsigned)nl[2] | ((unsigned)nl[3]<<16);
            ol.z = (unsigned)nl[4] | ((unsigned)nl[5]<<16);
            ol.w = (unsigned)nl[6] | ((unsigned)nl[7]<<16);
            *(uint4*)&Ah[row*72 + ch] = oh;
            *(uint4*)&Al[row*72 + ch] = ol;
        }
        #pragma unroll
        for (int e = 0; e < 4; ++e){
            int id = t + e*256;
            int row = id >> 3, ch = (id & 7)*8;
            uint4 vh = *(const uint4*)&ZcT_hi[(size_t)row*N + kbs + ch];
            uint4 vl = *(const uint4*)&ZcT_lo[(size_t)row*N + kbs + ch];
            *(uint4*)&Zh[row*72 + ch] = vh;
            *(uint4*)&Zl[row*72 + ch] = vl;
        }
        __syncthreads();
        #pragma unroll
        for (int ks = 0; ks < 2; ++ks){
            int aoff = (w*16 + lr)*72 + ks*32 + lg*8;
            bf16x8 aH = *(const bf16x8*)&Ah[aoff];
            bf16x8 aL = *(const bf16x8*)&Al[aoff];
            #pragma unroll
            for (int tt = 0; tt < 8; ++tt){
                int zoff = (tt*16 + lr)*72 + ks*32 + lg*8;
                bf16x8 bH = *(const bf16x8*)&Zh[zoff];
                bf16x8 bL = *(const bf16x8*)&Zl[zoff];
                acc[tt] = mfma16x16x32(aH, bH, acc[tt]);
                acc[tt] = mfma16x16x32(aL, bH, acc[tt]);
                acc[tt] = mfma16x16x32(aH, bL, acc[tt]);
            }
        }
        __syncthreads();
    }
    #pragma unroll
    for (int tt = 0; tt < 8; ++tt){
        #pragma unroll
        for (int r = 0; r < 4; ++r){
            int gi = i0 + w*16 + lg*4 + r;        // C/D: row=(lane>>4)*4+reg
            Pe[(size_t)blockIdx.y*(N*EC) + (size_t)gi*EC + tt*16 + lr] = acc[tt][r];
        }
    }
}

// ==== k6: reduce Pe + scale + bias + lrelu -> out — r1 verified ====
__global__ __launch_bounds__(256) void k_embfinal(const float* __restrict__ Pe,
                                                  const float* __restrict__ dsum,
                                                  const float* __restrict__ bc,
                                                  const float* __restrict__ Wo,
                                                  const float* __restrict__ bo,
                                                  float* __restrict__ out){
    __shared__ float vs[2][EC];
    __shared__ float Wos[EC*NC];
    __shared__ float bos[NC];
    int t = threadIdx.x;
    for (int idx = t; idx < EC*NC; idx += 256) Wos[idx] = Wo[idx];
    if (t < NC) bos[t] = bo[t];
    int rr = t >> 7, f = t & 127;
    int i = blockIdx.x*2 + rr;
    size_t idx = (size_t)i*EC + f;
    float s = 0.f;
    #pragma unroll
    for (int kc = 0; kc < KC_EC; ++kc) s += Pe[(size_t)kc*(N*EC) + idx];
    float v = rsqrtf(dsum[i])*s + bc[f];
    vs[rr][f] = v > 0.f ? v : 0.01f*v;
    __syncthreads();
    if (t < 2*NC){
        int r = t / NC;
        int c = t - r*NC;
        float a = bos[c];
        #pragma unroll 8
        for (int f2 = 0; f2 < EC; ++f2) a += vs[r][f2]*Wos[f2*NC+c];
        out[(size_t)(blockIdx.x*2 + r)*NC + c] = a;
    }
}

extern "C" void kernel_launch(void* const* d_in, const int* in_sizes, int n_in,
                              void* d_out, int out_size, void* d_ws, size_t ws_size,
                              hipStream_t stream) {
    const float* time_features = (const float*)d_in[0];
    const float* tw            = (const float*)d_in[2];
    const float* freq_features = (const float*)d_in[3];
    const float* fw            = (const float*)d_in[4];
    const int*   labels        = (const int*)d_in[5];
    const int*   qsize         = (const int*)d_in[7];
    const float* Wt  = (const float*)d_in[8];
    const float* bt  = (const float*)d_in[9];
    const float* Wf  = (const float*)d_in[10];
    const float* bfv = (const float*)d_in[11];
    const float* Wc  = (const float*)d_in[12];
    const float* bc  = (const float*)d_in[13];
    const float* Wo  = (const float*)d_in[14];
    const float* bo  = (const float*)d_in[15];
    float* out = (float*)d_out;

    float* ws    = (float*)d_ws;
    float* degT  = ws;                         // N   (memset)
    float* degF  = degT + N;                   // N   (memset)
    float* dsum  = degF + N;                   // N   (memset)
    float* colsb = dsum + N;                   // 8
    float* Yt    = colsb + 8;                  // N*ET
    float* Yf    = Yt + (size_t)N*ET;          // N*ET
    float* feats = Yf + (size_t)N*ET;          // N*FS
    float* Zc    = feats + (size_t)N*FS;       // N*EC floats (2 bf16 planes)
    float* Aw    = Zc + (size_t)N*EC;          // N*N floats (2 bf16 planes)
    float* Pt    = Aw + (size_t)N*N;           // KC_ET*N*ET
    float* Pf    = Pt + (size_t)KC_ET*N*ET;    // KC_ET*N*ET
    float* Pe    = Pf + (size_t)KC_ET*N*ET;    // KC_EC*N*EC

    u16* ZcT_hi = (u16*)Zc;
    u16* ZcT_lo = ZcT_hi + (size_t)N*EC;
    u16* Aw_hi  = (u16*)Aw;
    u16* Aw_lo  = Aw_hi + (size_t)N*N;

    hipMemsetAsync(degT, 0, 3*N*sizeof(float), stream);
    k_deg_label_xw<<<1025, 256, 0, stream>>>(tw, fw, labels,
                                             time_features, Wt, freq_features, Wf,
                                             degT, degF, colsb, Yt, Yf);
    k_agg_et_m<<<dim3(N/64, KC_ET), 256, 0, stream>>>(tw, fw, Yt, Yf, degT, degF, Pt, Pf);
    k_feats_epi<<<(N*64)/256, 256, 0, stream>>>(Pt, Pf, Yt, Yf, degT, degF,
                                                bt, bfv, colsb, qsize, feats);
    k_aw_zc<<<1280, 256, 0, stream>>>(feats, Wc, Aw_hi, Aw_lo, ZcT_hi, ZcT_lo, dsum);
    k_agg_ec<<<dim3(N/64, KC_EC), 256, 0, stream>>>(Aw_hi, Aw_lo, ZcT_hi, ZcT_lo, dsum, Pe);
    k_embfinal<<<N/2, 256, 0, stream>>>(Pe, dsum, bc, Wo, bo, out);
}